// Round 3
// baseline (1206.678 us; speedup 1.0000x reference)
//
#include <hip/hip_runtime.h>

#define D 64
#define NB_MAX 4096   // max buckets supported by the one-wave scan (N <= 256k)

// ---------------- small utility kernels ----------------

__global__ void zero_i32(int* __restrict__ p, int n) {
    int i = blockIdx.x * blockDim.x + threadIdx.x;
    if (i < n) p[i] = 0;
}

__global__ void zero_f32(float* __restrict__ p, long n) {
    long i = (long)blockIdx.x * blockDim.x + threadIdx.x;
    long stride = (long)gridDim.x * blockDim.x;
    for (; i < n; i += stride) p[i] = 0.0f;
}

// deg[dst[e]] += 1
__global__ void hist_kernel(const int* __restrict__ dst, int* __restrict__ deg, int E) {
    int e = blockIdx.x * blockDim.x + threadIdx.x;
    if (e < E) atomicAdd(&deg[dst[e]], 1);
}

// norm = rsqrt(max(deg,1)); norm2 = norm^2; bucket_cnt[b] = sum of deg over b's 64 nodes
__global__ void norm_bucket_kernel(const int* __restrict__ deg,
                                   float* __restrict__ norm, float* __restrict__ norm2,
                                   int* __restrict__ bcnt, int N, int NB) {
    int i = blockIdx.x * blockDim.x + threadIdx.x;
    int d = (i < N) ? deg[i] : 0;
    if (i < N) {
        float df = (float)d;
        df = df < 1.0f ? 1.0f : df;
        float r = rsqrtf(df);
        norm[i] = r;
        norm2[i] = r * r;
    }
    // wave (64 aligned lanes) reduce -> bucket count
    int s = d;
    for (int o = 1; o < 64; o <<= 1) s += __shfl_xor(s, o, 64);
    int b = i >> 6;
    if ((threadIdx.x & 63) == 0 && b < NB) bcnt[b] = s;
}

// one-wave exclusive scan over NB bucket counts -> off (and a copy in fill)
__global__ void scan_buckets(const int* __restrict__ cnt, int* __restrict__ off,
                             int* __restrict__ fill, int NB, int E) {
    __shared__ int s[NB_MAX];
    int lane = threadIdx.x;            // blockDim.x == 64
    for (int i = lane; i < NB; i += 64) s[i] = cnt[i];
    __syncthreads();
    int chunk = (NB + 63) / 64;
    int beg = lane * chunk;
    int end = beg + chunk; if (end > NB) end = NB;
    int sum = 0;
    for (int i = beg; i < end; i++) { int v = s[i]; s[i] = sum; sum += v; }
    int incl = sum;
    for (int o = 1; o < 64; o <<= 1) {
        int t = __shfl_up(incl, o, 64);
        if (lane >= o) incl += t;
    }
    int excl = incl - sum;
    __syncthreads();
    for (int i = beg; i < end; i++) {
        int v = s[i] + excl;
        off[i] = v;
        fill[i] = v;
    }
    if (lane == 63) off[NB] = E;
}

// packed[pos] = src | (dst&63)<<24, pos = atomicAdd(fill[dst>>6], 1)
// writes within a bucket are contiguous -> L2 write-combining (only ~NB hot lines)
__global__ void bucket_fill(const int* __restrict__ src, const int* __restrict__ dst,
                            int* __restrict__ fill, int* __restrict__ packed, int E) {
    int e = blockIdx.x * blockDim.x + threadIdx.x;
    if (e < E) {
        int d = dst[e];
        int b = d >> 6;
        int pos = atomicAdd(&fill[b], 1);
        packed[pos] = src[e] | ((d & 63) << 24);
    }
}

// one block per bucket; 64x64 fp32 tile in LDS; per edge a 16-lane group loads
// one float4 of the src row and LDS-atomic-adds into row (dst&63).
// out[node] = (post?post[node]:1) * sum_e scale[src_e] * x[src_e]
__global__ __launch_bounds__(256) void gather_lds(const float* __restrict__ x,
                                                  const float* __restrict__ scale,
                                                  const int* __restrict__ off,
                                                  const int* __restrict__ packed,
                                                  const float* __restrict__ post,
                                                  float* __restrict__ out, int N) {
    __shared__ float acc[64 * D];      // 16 KB
    int b = blockIdx.x;
    int tid = threadIdx.x;

    float4* a4 = (float4*)acc;
    for (int i = tid; i < 64 * D / 4; i += 256)
        a4[i] = make_float4(0.f, 0.f, 0.f, 0.f);
    __syncthreads();

    int beg = off[b], end = off[b + 1];
    int lane = tid & 63;
    int w = tid >> 6;                  // wave 0..3
    int g = lane >> 4;                 // lane-group 0..3
    int sub = lane & 15;               // float4 slot within row

    for (int e = beg + w * 4 + g; e < end; e += 16) {
        int p = packed[e];
        int s = p & 0xFFFFFF;
        int r = (p >> 24) & 63;
        float sc = scale[s];
        float4 v = ((const float4*)(x + (long)s * D))[sub];
        float* row = &acc[r * D + sub * 4];
        atomicAdd(row + 0, v.x * sc);
        atomicAdd(row + 1, v.y * sc);
        atomicAdd(row + 2, v.z * sc);
        atomicAdd(row + 3, v.w * sc);
    }
    __syncthreads();

    // coalesced tile write-out with fused post-scale
    int base = b << 6;                 // first node of bucket
    float4* o4 = (float4*)(out + (long)base * D);
    for (int i = tid; i < 64 * D / 4; i += 256) {
        int node = base + (i >> 4);
        if (node < N) {
            float4 v = a4[i];
            if (post) {
                float pn = post[node];
                v.x *= pn; v.y *= pn; v.z *= pn; v.w *= pn;
            }
            o4[i] = v;
        }
    }
}

// ---------------- fallback (atomic push) ----------------

__global__ void deg_kernel_f(const int* __restrict__ dst, float* __restrict__ deg, int E) {
    int e = blockIdx.x * blockDim.x + threadIdx.x;
    if (e < E) unsafeAtomicAdd(&deg[dst[e]], 1.0f);
}

__global__ void norm_kernel_f(float* __restrict__ deg_norm, float* __restrict__ norm2, int N) {
    int i = blockIdx.x * blockDim.x + threadIdx.x;
    if (i < N) {
        float d = deg_norm[i];
        d = d < 1.0f ? 1.0f : d;
        float r = rsqrtf(d);
        deg_norm[i] = r;
        norm2[i] = r * r;
    }
}

__global__ void scatter_kernel(const float* __restrict__ x,
                               const float* __restrict__ scale,
                               const int* __restrict__ src,
                               const int* __restrict__ dst,
                               float* __restrict__ out, int E) {
    long idx = (long)blockIdx.x * blockDim.x + threadIdx.x;
    int e = (int)(idx >> 6);
    int lane = (int)(idx & 63);
    if (e < E) {
        int s = src[e];
        int d0 = dst[e];
        float v = x[(long)s * D + lane] * scale[s];
        unsafeAtomicAdd(&out[(long)d0 * D + lane], v);
    }
}

__global__ void scale_kernel(float* __restrict__ out, const float* __restrict__ norm, long n) {
    long i = (long)blockIdx.x * blockDim.x + threadIdx.x;
    if (i < n) out[i] *= norm[i >> 6];
}

// ---------------- launch ----------------

extern "C" void kernel_launch(void* const* d_in, const int* in_sizes, int n_in,
                              void* d_out, int out_size, void* d_ws, size_t ws_size,
                              hipStream_t stream) {
    const float* feat = (const float*)d_in[0];
    const int*   src  = (const int*)d_in[1];
    const int*   dst  = (const int*)d_in[2];
    float* out = (float*)d_out;

    const int N = in_sizes[0] / D;   // 100000
    const int E = in_sizes[1];       // 1200000
    const long ND = (long)N * D;
    const int NB = (N + 63) / 64;    // 64-node buckets

    // ws layout (4B elems):
    //   deg[N] | bcnt[NB] | off[NB+1] | fill[NB] | packed[E] | norm[N] | norm2[N] | pad | buf1[ND]
    long o_deg = 0;
    long o_bcnt = o_deg + N;
    long o_off = o_bcnt + NB;
    long o_fill = o_off + NB + 1;
    long o_packed = o_fill + NB;
    long o_norm = o_packed + E;
    long o_norm2 = o_norm + N;
    long o_buf1 = (o_norm2 + N + 3) & ~3L;   // 16B align
    size_t need = (size_t)(o_buf1 + ND) * 4;

    if (ws_size >= need && N < (1 << 24) && NB <= NB_MAX) {
        int*   base_i = (int*)d_ws;
        float* base_f = (float*)d_ws;
        int* deg    = base_i + o_deg;
        int* bcnt   = base_i + o_bcnt;
        int* off    = base_i + o_off;
        int* fill   = base_i + o_fill;
        int* packed = base_i + o_packed;
        float* norm  = base_f + o_norm;
        float* norm2 = base_f + o_norm2;
        float* buf1  = base_f + o_buf1;

        // zero deg + bcnt (contiguous)
        zero_i32<<<(N + NB + 255) / 256, 256, 0, stream>>>(deg, N + NB);
        hist_kernel<<<(E + 255) / 256, 256, 0, stream>>>(dst, deg, E);
        norm_bucket_kernel<<<(N + 255) / 256, 256, 0, stream>>>(deg, norm, norm2, bcnt, N, NB);
        scan_buckets<<<1, 64, 0, stream>>>(bcnt, off, fill, NB, E);
        bucket_fill<<<(E + 255) / 256, 256, 0, stream>>>(src, dst, fill, packed, E);

        // hop 1: buf1 = S(norm ⊙ feat)
        gather_lds<<<NB, 256, 0, stream>>>(feat, norm, off, packed, nullptr, buf1, N);
        // hop 2: out = norm ⊙ S(norm2 ⊙ buf1)
        gather_lds<<<NB, 256, 0, stream>>>(buf1, norm2, off, packed, norm, out, N);
    } else {
        // fallback: atomic push mode
        float* norm  = (float*)d_ws;
        float* norm2 = norm + N;
        float* buf1  = norm2 + N;

        long nz = 2L * N + ND;
        zero_f32<<<(int)((nz + 255) / 256), 256, 0, stream>>>((float*)d_ws, nz);
        zero_f32<<<(int)((ND + 255) / 256), 256, 0, stream>>>(out, ND);
        deg_kernel_f<<<(E + 255) / 256, 256, 0, stream>>>(dst, norm, E);
        norm_kernel_f<<<(N + 255) / 256, 256, 0, stream>>>(norm, norm2, N);
        long work = (long)E * D;
        int blocks = (int)((work + 255) / 256);
        scatter_kernel<<<blocks, 256, 0, stream>>>(feat, norm, src, dst, buf1, E);
        scatter_kernel<<<blocks, 256, 0, stream>>>(buf1, norm2, src, dst, out, E);
        scale_kernel<<<(int)((ND + 255) / 256), 256, 0, stream>>>(out, norm, ND);
    }
}

// Round 4
// 314.735 us; speedup vs baseline: 3.8339x; 3.8339x over previous
//
#include <hip/hip_runtime.h>

#define D 64
#define BSH 4                    // 16 nodes per bucket
#define BNODES (1 << BSH)
#define NB_MAX 8192              // scan LDS capacity (N <= 128k nodes)

// ---------------- small utility kernels ----------------

__global__ void zero_i32(int* __restrict__ p, int n) {
    int i = blockIdx.x * blockDim.x + threadIdx.x;
    if (i < n) p[i] = 0;
}

__global__ void zero_f32(float* __restrict__ p, long n) {
    long i = (long)blockIdx.x * blockDim.x + threadIdx.x;
    long stride = (long)gridDim.x * blockDim.x;
    for (; i < n; i += stride) p[i] = 0.0f;
}

// deg[dst[e]] += 1
__global__ void hist_kernel(const int* __restrict__ dst, int* __restrict__ deg, int E) {
    int e = blockIdx.x * blockDim.x + threadIdx.x;
    if (e < E) atomicAdd(&deg[dst[e]], 1);
}

// norm = rsqrt(max(deg,1)); norm2 = norm^2; bcnt[b] = sum of deg over b's 16 nodes
__global__ void norm_bucket_kernel(const int* __restrict__ deg,
                                   float* __restrict__ norm, float* __restrict__ norm2,
                                   int* __restrict__ bcnt, int N, int NB) {
    int i = blockIdx.x * blockDim.x + threadIdx.x;
    int d = (i < N) ? deg[i] : 0;
    if (i < N) {
        float df = (float)d;
        df = df < 1.0f ? 1.0f : df;
        float r = rsqrtf(df);
        norm[i] = r;
        norm2[i] = r * r;
    }
    // 16-lane segmented reduce -> bucket count
    int s = d;
    for (int o = 1; o < BNODES; o <<= 1) s += __shfl_xor(s, o, BNODES);
    int b = i >> BSH;
    if ((threadIdx.x & (BNODES - 1)) == 0 && b < NB) bcnt[b] = s;
}

// one-wave exclusive scan over NB bucket counts -> off (and a copy in fill)
__global__ void scan_buckets(const int* __restrict__ cnt, int* __restrict__ off,
                             int* __restrict__ fill, int NB, int E) {
    __shared__ int s[NB_MAX];
    int lane = threadIdx.x;            // blockDim.x == 64
    for (int i = lane; i < NB; i += 64) s[i] = cnt[i];
    __syncthreads();
    int chunk = (NB + 63) / 64;
    int beg = lane * chunk;
    int end = beg + chunk; if (end > NB) end = NB;
    int sum = 0;
    for (int i = beg; i < end; i++) { int v = s[i]; s[i] = sum; sum += v; }
    int incl = sum;
    for (int o = 1; o < 64; o <<= 1) {
        int t = __shfl_up(incl, o, 64);
        if (lane >= o) incl += t;
    }
    int excl = incl - sum;
    __syncthreads();
    for (int i = beg; i < end; i++) {
        int v = s[i] + excl;
        off[i] = v;
        fill[i] = v;
    }
    if (lane == 63) off[NB] = E;
}

// row_ptr[n] = off[n>>BSH] + exclusive prefix of deg within the 16-node bucket
__global__ void rowptr_kernel(const int* __restrict__ deg, const int* __restrict__ off,
                              int* __restrict__ row_ptr, int N, int E) {
    int n = blockIdx.x * blockDim.x + threadIdx.x;
    int d = (n < N) ? deg[n] : 0;
    int incl = d;
    int l16 = threadIdx.x & (BNODES - 1);
    for (int o = 1; o < BNODES; o <<= 1) {
        int t = __shfl_up(incl, o, BNODES);
        if (l16 >= o) incl += t;
    }
    if (n < N) row_ptr[n] = off[n >> BSH] + incl - d;
    if (n == N) row_ptr[N] = E;
}

// packed[pos] = src | local4<<28, pos = atomicAdd(fill[dst>>BSH], 1)
// only ~NB hot tail lines (~400 KB) -> stays in L2, write-combined
__global__ void bucket_fill(const int* __restrict__ src, const int* __restrict__ dst,
                            int* __restrict__ fill, int* __restrict__ packed, int E) {
    int e = blockIdx.x * blockDim.x + threadIdx.x;
    if (e < E) {
        int d = dst[e];
        int b = d >> BSH;
        int pos = atomicAdd(&fill[b], 1);
        packed[pos] = src[e] | ((d & (BNODES - 1)) << 28);
    }
}

// one block per bucket: place each bucket edge at its exact per-node CSR slot
__global__ __launch_bounds__(128) void sort_kernel(const int* __restrict__ packed,
                                                   const int* __restrict__ off,
                                                   const int* __restrict__ row_ptr,
                                                   int* __restrict__ csr, int N) {
    __shared__ int cnt[BNODES];
    __shared__ int base[BNODES];
    int b = blockIdx.x;
    int tid = threadIdx.x;
    if (tid < BNODES) {
        int node = (b << BSH) + tid;
        base[tid] = (node <= N) ? row_ptr[node] : 0;
        cnt[tid] = 0;
    }
    __syncthreads();
    int beg = off[b], end = off[b + 1];
    for (int e = beg + tid; e < end; e += 128) {
        int p = packed[e];
        int r = (unsigned)p >> 28;
        int s = p & 0x0FFFFFFF;
        int pos = base[r] + atomicAdd(&cnt[r], 1);
        csr[pos] = s;
    }
}

// pull-mode per-node gather (round-2 proven structure):
// one wave per node; 16-lane group g handles edges beg+g, beg+g+4, ...
// out[n] = post[n] * sum_e (HS ? scale[src_e] : 1) * x[src_e]
template <bool HS>
__global__ void gather_csr(const float* __restrict__ x,
                           const float* __restrict__ scale,
                           const int* __restrict__ row_ptr,
                           const int* __restrict__ csr,
                           const float* __restrict__ post,
                           float* __restrict__ out, int N) {
    long idx = (long)blockIdx.x * blockDim.x + threadIdx.x;
    int w = (int)(idx >> 6);
    if (w >= N) return;
    int lane = (int)(idx & 63);
    int g = lane >> 4;
    int sub = lane & 15;
    int beg = row_ptr[w], end = row_ptr[w + 1];
    float ax = 0.f, ay = 0.f, az = 0.f, aw = 0.f;
    for (int e = beg + g; e < end; e += 4) {
        int s = csr[e];
        float sc = HS ? scale[s] : 1.0f;
        float4 v = ((const float4*)(x + (long)s * D))[sub];
        ax += v.x * sc; ay += v.y * sc; az += v.z * sc; aw += v.w * sc;
    }
    ax += __shfl_xor(ax, 16, 64); ay += __shfl_xor(ay, 16, 64);
    az += __shfl_xor(az, 16, 64); aw += __shfl_xor(aw, 16, 64);
    ax += __shfl_xor(ax, 32, 64); ay += __shfl_xor(ay, 32, 64);
    az += __shfl_xor(az, 32, 64); aw += __shfl_xor(aw, 32, 64);
    if (g == 0) {
        float pn = post[w];
        float4 r; r.x = ax * pn; r.y = ay * pn; r.z = az * pn; r.w = aw * pn;
        ((float4*)(out + (long)w * D))[sub] = r;
    }
}

// ---------------- fallback (atomic push, round-1) ----------------

__global__ void deg_kernel_f(const int* __restrict__ dst, float* __restrict__ deg, int E) {
    int e = blockIdx.x * blockDim.x + threadIdx.x;
    if (e < E) unsafeAtomicAdd(&deg[dst[e]], 1.0f);
}

__global__ void norm_kernel_f(float* __restrict__ deg_norm, float* __restrict__ norm2, int N) {
    int i = blockIdx.x * blockDim.x + threadIdx.x;
    if (i < N) {
        float d = deg_norm[i];
        d = d < 1.0f ? 1.0f : d;
        float r = rsqrtf(d);
        deg_norm[i] = r;
        norm2[i] = r * r;
    }
}

__global__ void scatter_kernel(const float* __restrict__ x,
                               const float* __restrict__ scale,
                               const int* __restrict__ src,
                               const int* __restrict__ dst,
                               float* __restrict__ out, int E) {
    long idx = (long)blockIdx.x * blockDim.x + threadIdx.x;
    int e = (int)(idx >> 6);
    int lane = (int)(idx & 63);
    if (e < E) {
        int s = src[e];
        int d0 = dst[e];
        float v = x[(long)s * D + lane] * scale[s];
        unsafeAtomicAdd(&out[(long)d0 * D + lane], v);
    }
}

__global__ void scale_kernel(float* __restrict__ out, const float* __restrict__ norm, long n) {
    long i = (long)blockIdx.x * blockDim.x + threadIdx.x;
    if (i < n) out[i] *= norm[i >> 6];
}

// ---------------- launch ----------------

extern "C" void kernel_launch(void* const* d_in, const int* in_sizes, int n_in,
                              void* d_out, int out_size, void* d_ws, size_t ws_size,
                              hipStream_t stream) {
    const float* feat = (const float*)d_in[0];
    const int*   src  = (const int*)d_in[1];
    const int*   dst  = (const int*)d_in[2];
    float* out = (float*)d_out;

    const int N = in_sizes[0] / D;   // 100000
    const int E = in_sizes[1];       // 1200000
    const long ND = (long)N * D;
    const int NB = (N + BNODES - 1) >> BSH;   // 16-node buckets

    // ws layout (4B elems):
    //   deg[N] | bcnt[NB] | off[NB+1] | fill[NB] | row_ptr[N+1] | csr[E] |
    //   norm[N] | norm2[N] | pad | buf1[ND]  (packed[E] aliases buf1's start)
    long o_deg    = 0;
    long o_bcnt   = o_deg + N;
    long o_off    = o_bcnt + NB;
    long o_fill   = o_off + NB + 1;
    long o_rowptr = o_fill + NB;
    long o_csr    = o_rowptr + N + 1;
    long o_norm   = o_csr + E;
    long o_norm2  = o_norm + N;
    long o_buf1   = (o_norm2 + N + 3) & ~3L;   // 16B align
    long buf1_len = (ND > (long)E) ? ND : (long)E;
    size_t need = (size_t)(o_buf1 + buf1_len) * 4;

    if (ws_size >= need && N < (1 << 28) && NB <= NB_MAX) {
        int*   bi = (int*)d_ws;
        float* bf = (float*)d_ws;
        int* deg     = bi + o_deg;
        int* bcnt    = bi + o_bcnt;
        int* off     = bi + o_off;
        int* fill    = bi + o_fill;
        int* row_ptr = bi + o_rowptr;
        int* csr     = bi + o_csr;
        float* norm  = bf + o_norm;
        float* norm2 = bf + o_norm2;
        float* buf1  = bf + o_buf1;
        int* packed  = (int*)buf1;            // dead before gather1 writes buf1

        zero_i32<<<(N + NB + 255) / 256, 256, 0, stream>>>(deg, N + NB);
        hist_kernel<<<(E + 255) / 256, 256, 0, stream>>>(dst, deg, E);
        norm_bucket_kernel<<<(N + 255) / 256, 256, 0, stream>>>(deg, norm, norm2, bcnt, N, NB);
        scan_buckets<<<1, 64, 0, stream>>>(bcnt, off, fill, NB, E);
        rowptr_kernel<<<(N + 256) / 256, 256, 0, stream>>>(deg, off, row_ptr, N, E);
        bucket_fill<<<(E + 255) / 256, 256, 0, stream>>>(src, dst, fill, packed, E);
        sort_kernel<<<NB, 128, 0, stream>>>(packed, off, row_ptr, csr, N);

        long thr = (long)N * 64;
        int blocks = (int)((thr + 255) / 256);
        // hop 1: buf1 = norm2 ⊙ S(norm ⊙ feat)
        gather_csr<true><<<blocks, 256, 0, stream>>>(feat, norm, row_ptr, csr, norm2, buf1, N);
        // hop 2: out = norm ⊙ S(buf1)   (scales pre-folded into buf1)
        gather_csr<false><<<blocks, 256, 0, stream>>>(buf1, nullptr, row_ptr, csr, norm, out, N);
    } else {
        // fallback: atomic push mode (round-1, needs only 2N+ND floats)
        float* norm  = (float*)d_ws;
        float* norm2 = norm + N;
        float* buf1  = norm2 + N;

        long nz = 2L * N + ND;
        zero_f32<<<(int)((nz + 255) / 256), 256, 0, stream>>>((float*)d_ws, nz);
        zero_f32<<<(int)((ND + 255) / 256), 256, 0, stream>>>(out, ND);
        deg_kernel_f<<<(E + 255) / 256, 256, 0, stream>>>(dst, norm, E);
        norm_kernel_f<<<(N + 255) / 256, 256, 0, stream>>>(norm, norm2, N);
        long work = (long)E * D;
        int blocks = (int)((work + 255) / 256);
        scatter_kernel<<<blocks, 256, 0, stream>>>(feat, norm, src, dst, buf1, E);
        scatter_kernel<<<blocks, 256, 0, stream>>>(buf1, norm2, src, dst, out, E);
        scale_kernel<<<(int)((ND + 255) / 256), 256, 0, stream>>>(out, norm, ND);
    }
}

// Round 5
// 241.180 us; speedup vs baseline: 5.0032x; 1.3050x over previous
//
#include <hip/hip_runtime.h>

#define D 64
#define BSH2 8                   // 256 nodes per coarse bucket
#define NPB 256                  // nodes per bucket (1<<BSH2)
#define NB2_MAX 1024             // max coarse buckets (N <= 256k)
#define PCHUNK 4096              // edges per partition/hist block

// ---------------- utility ----------------

__global__ void zero_i32(int* __restrict__ p, int n) {
    int i = blockIdx.x * blockDim.x + threadIdx.x;
    if (i < n) p[i] = 0;
}

__global__ void zero_f32(float* __restrict__ p, long n) {
    long i = (long)blockIdx.x * blockDim.x + threadIdx.x;
    long stride = (long)gridDim.x * blockDim.x;
    for (; i < n; i += stride) p[i] = 0.0f;
}

// ---------------- build pipeline ----------------

// per-block LDS histogram of coarse buckets; flush to padded global counters
__global__ __launch_bounds__(256) void coarse_hist(const int* __restrict__ dst,
                                                   int* __restrict__ bcntp,  // stride 16
                                                   int E, int NB2) {
    __shared__ int lh[NB2_MAX];
    int tid = threadIdx.x;
    int c0 = blockIdx.x * PCHUNK;
    int c1 = c0 + PCHUNK; if (c1 > E) c1 = E;
    for (int i = tid; i < NB2; i += 256) lh[i] = 0;
    __syncthreads();
    for (int e = c0 + tid; e < c1; e += 256)
        atomicAdd(&lh[dst[e] >> BSH2], 1);
    __syncthreads();
    for (int i = tid; i < NB2; i += 256) {
        int c = lh[i];
        if (c) atomicAdd(&bcntp[i << 4], c);
    }
}

// one block: exclusive scan of NB2 (<=1024) padded counts -> off, and tails fillp
__global__ __launch_bounds__(256) void scan_coarse(const int* __restrict__ bcntp,
                                                   int* __restrict__ off,
                                                   int* __restrict__ fillp,
                                                   int NB2, int E) {
    __shared__ int s[256];
    int tid = threadIdx.x;
    int v[4]; int sum = 0;
    for (int j = 0; j < 4; j++) {
        int i = tid * 4 + j;
        int c = (i < NB2) ? bcntp[i << 4] : 0;
        v[j] = sum; sum += c;
    }
    s[tid] = sum;
    __syncthreads();
    for (int o = 1; o < 256; o <<= 1) {
        int t = (tid >= o) ? s[tid - o] : 0;
        __syncthreads();
        s[tid] += t;
        __syncthreads();
    }
    int excl = s[tid] - sum;
    for (int j = 0; j < 4; j++) {
        int i = tid * 4 + j;
        if (i < NB2) { int val = excl + v[j]; off[i] = val; fillp[i << 4] = val; }
    }
    if (tid == 0) off[NB2] = E;
}

// each block: LDS hist of its chunk, one padded atomic per bucket to reserve a
// contiguous range, then place edges. Every output line is written by one block
// only -> L2 write-combining, no cross-XCD ping-pong.
// packed = src | (dst & 255) << 20   (requires N <= 2^20)
__global__ __launch_bounds__(256) void partition_kernel(const int* __restrict__ src,
                                                        const int* __restrict__ dst,
                                                        int* __restrict__ fillp, // stride 16
                                                        int* __restrict__ packed,
                                                        int E, int NB2) {
    __shared__ int lhist[NB2_MAX];
    __shared__ int lbase[NB2_MAX];
    int tid = threadIdx.x;
    int c0 = blockIdx.x * PCHUNK;
    int c1 = c0 + PCHUNK; if (c1 > E) c1 = E;
    for (int i = tid; i < NB2; i += 256) lhist[i] = 0;
    __syncthreads();
    for (int e = c0 + tid; e < c1; e += 256)
        atomicAdd(&lhist[dst[e] >> BSH2], 1);
    __syncthreads();
    for (int i = tid; i < NB2; i += 256) {
        int c = lhist[i];
        lbase[i] = c ? atomicAdd(&fillp[i << 4], c) : 0;
    }
    __syncthreads();
    for (int e = c0 + tid; e < c1; e += 256) {
        int d = dst[e];
        int k = d >> BSH2;
        int pos = atomicAdd(&lbase[k], 1);
        packed[pos] = src[e] | ((d & (NPB - 1)) << 20);
    }
}

// one block per coarse bucket: per-node counts (LDS) -> in-block scan gives
// row_ptr + deg (fused norm/norm2), second sweep places csr entries.
__global__ __launch_bounds__(256) void bucket_csr(const int* __restrict__ packed,
                                                  const int* __restrict__ off,
                                                  int* __restrict__ row_ptr,
                                                  float* __restrict__ norm,
                                                  float* __restrict__ norm2,
                                                  int* __restrict__ csr,
                                                  int N, int NB2) {
    __shared__ int cnt[NPB];
    __shared__ int pre[NPB];
    int b = blockIdx.x;
    int tid = threadIdx.x;
    cnt[tid] = 0;
    __syncthreads();
    int beg = off[b], end = off[b + 1];
    for (int e = beg + tid; e < end; e += 256)
        atomicAdd(&cnt[(packed[e] >> 20) & (NPB - 1)], 1);
    __syncthreads();
    int v = cnt[tid];
    pre[tid] = v;
    __syncthreads();
    for (int o = 1; o < 256; o <<= 1) {
        int t = (tid >= o) ? pre[tid - o] : 0;
        __syncthreads();
        pre[tid] += t;
        __syncthreads();
    }
    int excl = pre[tid] - v;
    int node = (b << BSH2) + tid;
    if (node < N) {
        row_ptr[node] = beg + excl;
        float df = (float)v; df = df < 1.0f ? 1.0f : df;
        float r = rsqrtf(df);
        norm[node] = r;
        norm2[node] = r * r;
    }
    if (b == NB2 - 1 && tid == 0) row_ptr[N] = end;   // == E
    // reuse cnt as running placement cursor
    cnt[tid] = beg + excl;
    __syncthreads();
    for (int e = beg + tid; e < end; e += 256) {
        int p = packed[e];
        int pos = atomicAdd(&cnt[(p >> 20) & (NPB - 1)], 1);
        csr[pos] = p & 0xFFFFF;
    }
}

// ---------------- gather (proven round-2/4 structure) ----------------

template <bool HS>
__global__ void gather_csr(const float* __restrict__ x,
                           const float* __restrict__ scale,
                           const int* __restrict__ row_ptr,
                           const int* __restrict__ csr,
                           const float* __restrict__ post,
                           float* __restrict__ out, int N) {
    long idx = (long)blockIdx.x * blockDim.x + threadIdx.x;
    int w = (int)(idx >> 6);
    if (w >= N) return;
    int lane = (int)(idx & 63);
    int g = lane >> 4;
    int sub = lane & 15;
    int beg = row_ptr[w], end = row_ptr[w + 1];
    float ax = 0.f, ay = 0.f, az = 0.f, aw = 0.f;
    for (int e = beg + g; e < end; e += 4) {
        int s = csr[e];
        float sc = HS ? scale[s] : 1.0f;
        float4 v = ((const float4*)(x + (long)s * D))[sub];
        ax += v.x * sc; ay += v.y * sc; az += v.z * sc; aw += v.w * sc;
    }
    ax += __shfl_xor(ax, 16, 64); ay += __shfl_xor(ay, 16, 64);
    az += __shfl_xor(az, 16, 64); aw += __shfl_xor(aw, 16, 64);
    ax += __shfl_xor(ax, 32, 64); ay += __shfl_xor(ay, 32, 64);
    az += __shfl_xor(az, 32, 64); aw += __shfl_xor(aw, 32, 64);
    if (g == 0) {
        float pn = post[w];
        float4 r; r.x = ax * pn; r.y = ay * pn; r.z = az * pn; r.w = aw * pn;
        ((float4*)(out + (long)w * D))[sub] = r;
    }
}

// ---------------- fallback (atomic push, round-1) ----------------

__global__ void deg_kernel_f(const int* __restrict__ dst, float* __restrict__ deg, int E) {
    int e = blockIdx.x * blockDim.x + threadIdx.x;
    if (e < E) unsafeAtomicAdd(&deg[dst[e]], 1.0f);
}

__global__ void norm_kernel_f(float* __restrict__ deg_norm, float* __restrict__ norm2, int N) {
    int i = blockIdx.x * blockDim.x + threadIdx.x;
    if (i < N) {
        float d = deg_norm[i];
        d = d < 1.0f ? 1.0f : d;
        float r = rsqrtf(d);
        deg_norm[i] = r;
        norm2[i] = r * r;
    }
}

__global__ void scatter_kernel(const float* __restrict__ x,
                               const float* __restrict__ scale,
                               const int* __restrict__ src,
                               const int* __restrict__ dst,
                               float* __restrict__ out, int E) {
    long idx = (long)blockIdx.x * blockDim.x + threadIdx.x;
    int e = (int)(idx >> 6);
    int lane = (int)(idx & 63);
    if (e < E) {
        int s = src[e];
        int d0 = dst[e];
        float v = x[(long)s * D + lane] * scale[s];
        unsafeAtomicAdd(&out[(long)d0 * D + lane], v);
    }
}

__global__ void scale_kernel(float* __restrict__ out, const float* __restrict__ norm, long n) {
    long i = (long)blockIdx.x * blockDim.x + threadIdx.x;
    if (i < n) out[i] *= norm[i >> 6];
}

// ---------------- launch ----------------

extern "C" void kernel_launch(void* const* d_in, const int* in_sizes, int n_in,
                              void* d_out, int out_size, void* d_ws, size_t ws_size,
                              hipStream_t stream) {
    const float* feat = (const float*)d_in[0];
    const int*   src  = (const int*)d_in[1];
    const int*   dst  = (const int*)d_in[2];
    float* out = (float*)d_out;

    const int N = in_sizes[0] / D;   // 100000
    const int E = in_sizes[1];       // 1200000
    const long ND = (long)N * D;
    const int NB2 = (N + NPB - 1) >> BSH2;   // coarse buckets

    // ws layout (4B elems):
    //   bcntp[NB2_MAX*16] | fillp[NB2_MAX*16] | off[NB2+1] | row_ptr[N+1] |
    //   csr[E] | norm[N] | norm2[N] | pad | buf1[max(ND,E)]
    //   (packed[E] aliases buf1 -- dead before gather1 writes buf1)
    long o_bcntp = 0;
    long o_fillp = o_bcntp + NB2_MAX * 16;
    long o_off   = o_fillp + NB2_MAX * 16;
    long o_rowp  = o_off + NB2 + 1;
    long o_csr   = o_rowp + N + 1;
    long o_norm  = o_csr + E;
    long o_norm2 = o_norm + N;
    long o_buf1  = (o_norm2 + N + 3) & ~3L;   // 16B align
    long buf1_len = (ND > (long)E) ? ND : (long)E;
    size_t need = (size_t)(o_buf1 + buf1_len) * 4;

    if (ws_size >= need && N <= (1 << 20) && NB2 <= NB2_MAX) {
        int*   bi = (int*)d_ws;
        float* bf = (float*)d_ws;
        int* bcntp   = bi + o_bcntp;
        int* fillp   = bi + o_fillp;
        int* off     = bi + o_off;
        int* row_ptr = bi + o_rowp;
        int* csr     = bi + o_csr;
        float* norm  = bf + o_norm;
        float* norm2 = bf + o_norm2;
        float* buf1  = bf + o_buf1;
        int* packed  = (int*)buf1;

        int pblocks = (E + PCHUNK - 1) / PCHUNK;

        zero_i32<<<(NB2_MAX * 16 + 255) / 256, 256, 0, stream>>>(bcntp, NB2_MAX * 16);
        coarse_hist<<<pblocks, 256, 0, stream>>>(dst, bcntp, E, NB2);
        scan_coarse<<<1, 256, 0, stream>>>(bcntp, off, fillp, NB2, E);
        partition_kernel<<<pblocks, 256, 0, stream>>>(src, dst, fillp, packed, E, NB2);
        bucket_csr<<<NB2, 256, 0, stream>>>(packed, off, row_ptr, norm, norm2, csr, N, NB2);

        long thr = (long)N * 64;
        int gblocks = (int)((thr + 255) / 256);
        // hop 1: buf1 = norm2 ⊙ S(norm ⊙ feat)
        gather_csr<true><<<gblocks, 256, 0, stream>>>(feat, norm, row_ptr, csr, norm2, buf1, N);
        // hop 2: out = norm ⊙ S(buf1)
        gather_csr<false><<<gblocks, 256, 0, stream>>>(buf1, nullptr, row_ptr, csr, norm, out, N);
    } else {
        // fallback: atomic push mode
        float* norm  = (float*)d_ws;
        float* norm2 = norm + N;
        float* buf1  = norm2 + N;

        long nz = 2L * N + ND;
        zero_f32<<<(int)((nz + 255) / 256), 256, 0, stream>>>((float*)d_ws, nz);
        zero_f32<<<(int)((ND + 255) / 256), 256, 0, stream>>>(out, ND);
        deg_kernel_f<<<(E + 255) / 256, 256, 0, stream>>>(dst, norm, E);
        norm_kernel_f<<<(N + 255) / 256, 256, 0, stream>>>(norm, norm2, N);
        long work = (long)E * D;
        int blocks = (int)((work + 255) / 256);
        scatter_kernel<<<blocks, 256, 0, stream>>>(feat, norm, src, dst, buf1, E);
        scatter_kernel<<<blocks, 256, 0, stream>>>(buf1, norm2, src, dst, out, E);
        scale_kernel<<<(int)((ND + 255) / 256), 256, 0, stream>>>(out, norm, ND);
    }
}